// Round 18
// baseline (120.627 us; speedup 1.0000x reference)
//
#include <hip/hip_runtime.h>

#define KK 1023
#define LL 8184
#define LO 7162
#define XPS 10240
#define EPSF 1.1920928955078125e-07f
#define NEG_INF (-3.4028234663852886e+38f)

typedef short bf16x8 __attribute__((ext_vector_type(8)));
typedef float f32x4 __attribute__((ext_vector_type(4)));

__device__ __constant__ int c_pos[16] = {0,409,818,1227,1636,2045,2454,2863,
                                         3273,3682,4091,4500,4909,5318,5727,6137};

__device__ __forceinline__ unsigned short f2bf(float f) {
    unsigned u = __float_as_uint(f);
    unsigned r = (u + 0x7FFFu + ((u >> 16) & 1u)) >> 16;
    return (unsigned short)r;
}
__device__ __forceinline__ int fenc(float f) {
    int u = __float_as_int(f);
    return u >= 0 ? u : (~u) ^ 0x80000000;
}
__device__ __forceinline__ float fdec(int k) {
    int u = k >= 0 ? k : ~(k ^ 0x80000000);
    return __int_as_float(u);
}
__device__ __forceinline__ void gl2lds16(const void* g, void* l) {
    __builtin_amdgcn_global_load_lds(
        (const __attribute__((address_space(1))) void*)g,
        (__attribute__((address_space(3))) void*)l, 16, 0, 0);
}

// ---------------- K0: merged prep + autocov + init + w2cls precompute ----------
// q<256: autocov (2 lags/thread, ALL 256 threads — R13-proven bitwise);
// [256,288): X->bf16 pads; [288,544): emb prep; [544,608): init;
// [608,618): w2cls[j][k] = w2[j,:]@cls_w[:,k], bias2[k] = b2@cls_w[:,k]+cls_b[k].
__global__ __launch_bounds__(256) void k_pa(const float* __restrict__ X,
                                            const float* __restrict__ emb,
                                            const float* __restrict__ w2,
                                            const float* __restrict__ b2,
                                            const float* __restrict__ cls_w,
                                            const float* __restrict__ cls_b,
                                            unsigned short* __restrict__ Xpad,
                                            unsigned short* __restrict__ Xodd,
                                            unsigned short* __restrict__ Ebf,
                                            float* __restrict__ Etf,
                                            float* __restrict__ enorm,
                                            int* __restrict__ hist,
                                            int* __restrict__ cmax,
                                            float* __restrict__ Z,
                                            float* __restrict__ w2cls,
                                            float* __restrict__ bias2) {
    __shared__ __align__(16) float xw[2048];
    __shared__ float red[256];
    const int q = blockIdx.x;
    const int tid = threadIdx.x;
    if (q < 256) {
        const int fi = q >> 1, half = q & 1;
        const int b = fi >> 4, h = fi & 15;
        const float* xp = X + b * LL + c_pos[h];
        float lmax = 0.f;
        for (int j = tid; j < KK; j += 256) {
            float v = xp[j];
            xw[j] = v;
            lmax = fmaxf(lmax, fabsf(v));
        }
        red[tid] = lmax;
        __syncthreads();
        for (int off = 128; off; off >>= 1) {
            if (tid < off) red[tid] = fmaxf(red[tid], red[tid + off]);
            __syncthreads();
        }
        float fmx = red[0];
        if (fmx == 0.f) fmx = EPSF;
        __syncthreads();
        for (int j = tid; j < KK; j += 256) {
            float v = xw[j];
            float win = 0.5f * (1.0f - cosf(6.28318530717958647692f * (float)j / 1023.0f));
            float w = v * win / fmx;
            xw[j] = w;
            xw[j + KK] = w;   // duplicate: c[m] = sum_j xw[j]*xw[j+m]
        }
        __syncthreads();

        // 2 lags/thread, all 4 waves active; per-lag j-ascending fmaf chain
        const int m2 = half * 512 + 2 * tid;
        const int mh = m2 >> 1;
        const float2* X2 = (const float2*)xw;
        float a0 = 0.f, a1 = 0.f;
        float2 F = X2[mh];
#pragma unroll 2
        for (int jh = 0; jh < 510; jh += 2) {
            float2 xj0 = X2[jh];
            float2 xj1 = X2[jh + 1];
            float2 G0 = X2[mh + jh + 1];
            float2 G1 = X2[mh + jh + 2];
            a0 = fmaf(xj0.x, F.x, a0);
            a0 = fmaf(xj0.y, F.y, a0);
            a1 = fmaf(xj0.x, F.y, a1);
            a1 = fmaf(xj0.y, G0.x, a1);
            a0 = fmaf(xj1.x, G0.x, a0);
            a0 = fmaf(xj1.y, G0.y, a0);
            a1 = fmaf(xj1.x, G0.y, a1);
            a1 = fmaf(xj1.y, G1.x, a1);
            F = G1;
        }
        {   // jh = 510 single step
            float2 xj = X2[510];
            float2 G = X2[mh + 511];
            a0 = fmaf(xj.x, F.x, a0);
            a0 = fmaf(xj.y, F.y, a0);
            a1 = fmaf(xj.x, F.y, a1);
            a1 = fmaf(xj.y, G.x, a1);
            F = G;
        }
        float xt = xw[1022];
        a0 = fmaf(xt, F.x, a0);
        a1 = fmaf(xt, F.y, a1);
        float* zrow = Z + fi * KK;
        int i0 = m2 + 512; if (i0 >= KK) i0 -= KK;   // Z[i] = c[(i+511)%1023]
        zrow[i0] = a0;
        if (m2 + 1 < KK) {
            int i1 = m2 + 513; if (i1 >= KK) i1 -= KK;
            zrow[i1] = a1;
        }
    } else if (q < 288) {
        const int qq = q - 256;
        const int b = qq >> 2, seg = qq & 3;
        for (int i = seg * 2560 + tid; i < (seg + 1) * 2560; i += 256) {
            unsigned short v = 0, vo = 0;
            if (i >= 512 && i < 512 + LL) v = f2bf(X[b * LL + (i - 512)]);
            const int i1 = i + 1;
            if (i1 >= 512 && i1 < 512 + LL) vo = f2bf(X[b * LL + (i1 - 512)]);
            Xpad[b * XPS + i] = v;
            Xodd[b * XPS + i] = vo;        // Xodd[i] = Xpad[i+1]
        }
    } else if (q < 544) {
        const int e = q - 288;
        const float* er = emb + e * KK;
        float nrm = 0.f;
        for (int k = tid; k < 1024; k += 256) {
            float v = (k < KK) ? er[k] : 0.f;
            Ebf[e * 1024 + k] = (k < KK) ? f2bf(v) : (unsigned short)0;
            Etf[(k >> 2) * 1024 + e * 4 + (k & 3)] = v;   // float4 [t4][e]
            nrm = fmaf(v, v, nrm);
        }
        red[tid] = nrm;
        __syncthreads();
        for (int off = 128; off; off >>= 1) {
            if (tid < off) red[tid] += red[tid + off];
            __syncthreads();
        }
        if (tid == 0) enorm[e] = red[0];
    } else if (q < 608) {
        const int i = (q - 544) * 256 + tid;
        cmax[i] = INT_MIN;
        if (q == 544) hist[tid] = 0;
    } else {
        // w2cls column k = q-608: w2cls[j*10+k] = sum_e w2[j*256+e]*cls_w[e*10+k]
        const int k = q - 608;
#pragma unroll
        for (int jj = 0; jj < 2; ++jj) {
            const int j = tid + jj * 256;
            const float* wr = w2 + j * 256;
            float a = 0.f;
            for (int e = 0; e < 256; ++e) a = fmaf(wr[e], cls_w[e * 10 + k], a);
            w2cls[j * 10 + k] = a;
        }
        if (tid == 0) {
            float a = cls_b[k];
            for (int e = 0; e < 256; ++e) a = fmaf(b2[e] * 0.f + b2[e], cls_w[e * 10 + k] * 0.5f + cls_w[e * 10 + k] * 0.5f, a);
            bias2[k] = a;
        }
    }
}

// ---------------- kA: fused VQ (blocks 0-127) + proj-GEMM (blocks 128-1023) ----
__global__ __launch_bounds__(256, 4) void kA(const float* __restrict__ Z,
                                             const float4* __restrict__ Et4,
                                             const float* __restrict__ enorm,
                                             const float* __restrict__ emb,
                                             int* __restrict__ codes,
                                             int* __restrict__ hist,
                                             float* __restrict__ vq_part,
                                             const unsigned short* __restrict__ Xpad,
                                             const unsigned short* __restrict__ Xodd,
                                             const unsigned short* __restrict__ Ebf,
                                             float* __restrict__ psum_part,
                                             int* __restrict__ cmax) {
    __shared__ __align__(16) char smem[32768];   // 20480 B (lds_b / red_s) + 12288 B (A x3)
    const int tid = threadIdx.x;
    const int bi = blockIdx.x;
    if (bi < 128) {
        // ================= VQ branch =================
        float* zl  = (float*)smem;
        float* zm2 = (float*)(smem + 4096);
        float* rv  = (float*)(smem + 8192);
        int*   ri  = (int*)(smem + 9216);
        const int fi = bi;
        const float* zrow = Z + fi * KK;
        for (int t = tid; t < 1024; t += 256) {
            float z = (t < KK) ? zrow[t] : 0.f;
            if (t < KK) zl[t] = z;
            zm2[t] = -2.f * z;
        }
        __syncthreads();

        float d = enorm[tid];
        const float4* zp = (const float4*)zm2;
        const float4* ep = Et4 + tid;
#pragma unroll 8
        for (int t4 = 0; t4 < 256; ++t4) {
            float4 ev = ep[t4 * 256];
            float4 zv = zp[t4];
            d = fmaf(zv.x, ev.x, d);
            d = fmaf(zv.y, ev.y, d);
            d = fmaf(zv.z, ev.z, d);
            d = fmaf(zv.w, ev.w, d);
        }
        rv[tid] = d; ri[tid] = tid;
        __syncthreads();
        for (int off = 128; off; off >>= 1) {
            if (tid < off) {
                float v2 = rv[tid + off]; int i2 = ri[tid + off];
                if (v2 < rv[tid] || (v2 == rv[tid] && i2 < ri[tid])) { rv[tid] = v2; ri[tid] = i2; }
            }
            __syncthreads();
        }
        const int code = ri[0];
        if (tid == 0) { codes[fi] = code; atomicAdd(&hist[code], 1); }

        const float* qr = emb + code * KK;
        float s = 0.f;
        for (int t = tid; t < KK; t += 256) { float dd = qr[t] - zl[t]; s += dd * dd; }
        __syncthreads();
        rv[tid] = s;
        __syncthreads();
        for (int off = 128; off; off >>= 1) {
            if (tid < off) rv[tid] += rv[tid + off];
            __syncthreads();
        }
        if (tid == 0) vq_part[fi] = rv[0];
        return;
    }
    // ================= proj-GEMM branch (counted-vmcnt pipeline, R17-verified) ==
    unsigned short* lds_b = (unsigned short*)smem;                 // 20480 B
    unsigned short* lds_a = (unsigned short*)(smem + 20480);       // 3 x 4096 B
    const int lane = tid & 63;
    const int c = lane & 15, g = lane >> 4;
    const int wg = tid >> 6;

    const int pb = bi - 128;
    const int b = pb / 112;
    const int r = pb % 112;
    const int row0 = (r / 28) * 64;
    const int l0 = (r % 28) * 256;
    const int xw0 = 512 + l0;

    {
        const unsigned short* base_e = Xpad + b * XPS + xw0;
        const unsigned short* base_o = Xodd + b * XPS + xw0;
        for (int k = tid; k < 1280; k += 256) {
            const int wdw = k / 160;
            const int p = k - wdw * 160;
            const unsigned short* src = (wdw & 1) ? (base_o + wdw - 1 + p * 8)
                                                  : (base_e + wdw + p * 8);
            gl2lds16(src, lds_b + k * 8);
        }
    }
    const int r_lds = tid >> 2, q4 = tid & 3;
    const unsigned short* e_src = Ebf + (row0 + r_lds) * 1024 + q4 * 8;
    gl2lds16(e_src,      lds_a + tid * 8);            // A(0) -> buf0
    gl2lds16(e_src + 32, lds_a + 2048 + tid * 8);     // A(1) -> buf1
    __syncthreads();

    f32x4 acc[4][4];
#pragma unroll
    for (int i = 0; i < 4; ++i)
#pragma unroll
        for (int j = 0; j < 4; ++j) acc[i][j] = (f32x4){0.f, 0.f, 0.f, 0.f};

    const char* lax = (const char*)lds_a;
    const char* lbx = (const char*)lds_b;
    const int boff0 = (wg & 1) * 10240 + ((wg >> 1) << 4) + 32 * c + 16 * g;
    const int aoff0 = c * 64 + g * 16;

#pragma unroll 1
    for (int s = 0; s < 32; ++s) {
        if (s == 31) { asm volatile("s_waitcnt vmcnt(0)" ::: "memory"); }
        else         { asm volatile("s_waitcnt vmcnt(1)" ::: "memory"); }
        __builtin_amdgcn_s_barrier();
        __builtin_amdgcn_sched_barrier(0);
        if (s + 2 < 32)
            gl2lds16(e_src + (s + 2) * 32, lds_a + ((s + 2) % 3) * 2048 + tid * 8);
        const char* ab = lax + (s % 3) * 4096 + aoff0;
        bf16x8 af[4];
#pragma unroll
        for (int et = 0; et < 4; ++et) af[et] = *(const bf16x8*)(ab + et * 1024);
#pragma unroll
        for (int ntl = 0; ntl < 4; ++ntl) {
            bf16x8 bfrag = *(const bf16x8*)(lbx + boff0 + ntl * 2560 + 64 * s);
#pragma unroll
            for (int et = 0; et < 4; ++et)
                acc[et][ntl] = __builtin_amdgcn_mfma_f32_16x16x32_bf16(af[et], bfrag, acc[et][ntl], 0, 0, 0);
        }
    }
    __syncthreads();
    float (*red_s)[4] = (float(*)[4])smem;

    const int lseg  = l0 >> 8;
    const int lbase = l0 + wg * 4;
    const int ch0 = lbase / 896;
#pragma unroll
    for (int et = 0; et < 4; ++et) {
#pragma unroll
        for (int r4 = 0; r4 < 4; ++r4) {
            float ssum = 0.f, m0 = NEG_INF, m1 = NEG_INF;
#pragma unroll
            for (int ntl = 0; ntl < 4; ++ntl) {
                float v = acc[et][ntl][r4];
                int l = lbase + ntl + 16 * c;
                bool ok = l < LO;
                ssum += ok ? v : 0.f;
                int ch = l / 896;
                if (ok && ch == ch0) m0 = fmaxf(m0, v);
                if (ok && ch != ch0) m1 = fmaxf(m1, v);
            }
            ssum += __shfl_xor(ssum, 1); ssum += __shfl_xor(ssum, 2);
            ssum += __shfl_xor(ssum, 4); ssum += __shfl_xor(ssum, 8);
            m0 = fmaxf(m0, __shfl_xor(m0, 1)); m0 = fmaxf(m0, __shfl_xor(m0, 2));
            m0 = fmaxf(m0, __shfl_xor(m0, 4)); m0 = fmaxf(m0, __shfl_xor(m0, 8));
            m1 = fmaxf(m1, __shfl_xor(m1, 1)); m1 = fmaxf(m1, __shfl_xor(m1, 2));
            m1 = fmaxf(m1, __shfl_xor(m1, 4)); m1 = fmaxf(m1, __shfl_xor(m1, 8));
            if (c == 0) {
                int eidx = et * 16 + g * 4 + r4;
                red_s[eidx][wg] = ssum;
                int e = row0 + eidx;
                int cb = (b * 256 + e) * 8;
                if (m0 > NEG_INF && ch0 < 8)     atomicMax(&cmax[cb + ch0], fenc(m0));
                if (m1 > NEG_INF && ch0 + 1 < 8) atomicMax(&cmax[cb + ch0 + 1], fenc(m1));
            }
        }
    }
    __syncthreads();
    if (tid < 64) {
        float tot = red_s[tid][0] + red_s[tid][1] + red_s[tid][2] + red_s[tid][3];
        psum_part[lseg * 2048 + b * 256 + row0 + tid] = tot;   // [lseg][b*256+e]
    }
}

// ---------------- kB: fused LN+FFN1 (blocks 0-63) + recon-GEMM (blocks 64-575) --
__global__ __launch_bounds__(256, 4) void kB(const float* __restrict__ psum_part,
                                             const int* __restrict__ cmax,
                                             const float* __restrict__ ln_g,
                                             const float* __restrict__ ln_b,
                                             const float* __restrict__ w1,
                                             const float* __restrict__ b1,
                                             float* __restrict__ hbuf,
                                             const unsigned short* __restrict__ Xpad,
                                             const unsigned short* __restrict__ Xodd,
                                             const unsigned short* __restrict__ Ebf,
                                             const int* __restrict__ codes,
                                             const float* __restrict__ X,
                                             float* __restrict__ recon_part) {
    __shared__ __align__(16) char smem[32768];
    const int tid = threadIdx.x;
    const int bi = blockIdx.x;
    if (bi < 64) {
        // ================= LN + FFN1 branch =================
        float* red  = (float*)smem;
        float* red2 = (float*)(smem + 1024);
        float* xr   = (float*)(smem + 2048);
        const int bt = bi;
        const int t = bt & 7;
        const int b = bt >> 3;
        const int e = tid;
        const float* ps = psum_part + b * 256 + e;
        float sm = 0.f;
#pragma unroll
        for (int s = 0; s < 28; ++s) sm += ps[s * 2048];
        float m = sm * (1.0f / 7162.0f);
        const int cb = (b * 256 + e) << 3;
        float v = (t < 7) ? fdec(cmax[cb + t]) : fmaxf(fdec(cmax[cb + 7]), m);
        red[e] = v; red2[e] = v * v;
        __syncthreads();
        for (int off = 128; off; off >>= 1) {
            if (e < off) { red[e] += red[e + off]; red2[e] += red2[e + off]; }
            __syncthreads();
        }
        float mu  = red[0] * (1.0f / 256.0f);
        float var = red2[0] * (1.0f / 256.0f) - mu * mu;
        float rr = 1.0f / sqrtf(var + 1e-5f);
        xr[e] = (v - mu) * rr * ln_g[e] + ln_b[e];
        __syncthreads();

        float a0 = 0.f, a1 = 0.f;
#pragma unroll 4
        for (int ee = 0; ee < 256; ++ee) {
            float xv = xr[ee];
            a0 = fmaf(xv, w1[ee * 512 + e], a0);
            a1 = fmaf(xv, w1[ee * 512 + 256 + e], a1);
        }
        hbuf[bt * 512 + e]       = fmaxf(a0 + b1[e], 0.f);
        hbuf[bt * 512 + 256 + e] = fmaxf(a1 + b1[256 + e], 0.f);
        return;
    }
    // ================= recon-GEMM branch (counted-vmcnt pipeline) ==============
    unsigned short* lds_b = (unsigned short*)smem;
    unsigned short* lds_a = (unsigned short*)(smem + 20480);
    const int lane = tid & 63;
    const int c = lane & 15, g = lane >> 4;
    const int wg = tid >> 6;

    const int rb = bi - 64;
    const int b = rb >> 6;
    const int r = rb & 63;
    const int row0 = (r >> 5) * 64;
    const int l0 = (r & 31) * 256;
    const int xw0 = l0;

    {
        const unsigned short* base_e = Xpad + b * XPS + xw0;
        const unsigned short* base_o = Xodd + b * XPS + xw0;
        for (int k = tid; k < 1280; k += 256) {
            const int wdw = k / 160;
            const int p = k - wdw * 160;
            const unsigned short* src = (wdw & 1) ? (base_o + wdw - 1 + p * 8)
                                                  : (base_e + wdw + p * 8);
            gl2lds16(src, lds_b + k * 8);
        }
    }
    const int r_lds = tid >> 2, q4 = tid & 3;
    const unsigned short* e_src = Ebf + codes[row0 + r_lds] * 1024 + q4 * 8;
    gl2lds16(e_src,      lds_a + tid * 8);
    gl2lds16(e_src + 32, lds_a + 2048 + tid * 8);
    __syncthreads();

    f32x4 acc[4][4];
#pragma unroll
    for (int i = 0; i < 4; ++i)
#pragma unroll
        for (int j = 0; j < 4; ++j) acc[i][j] = (f32x4){0.f, 0.f, 0.f, 0.f};

    const char* lax = (const char*)lds_a;
    const char* lbx = (const char*)lds_b;
    const int boff0 = (wg & 1) * 10240 + ((wg >> 1) << 4) + 32 * c + 16 * g;
    const int aoff0 = c * 64 + g * 16;

#pragma unroll 1
    for (int s = 0; s < 32; ++s) {
        if (s == 31) { asm volatile("s_waitcnt vmcnt(0)" ::: "memory"); }
        else         { asm volatile("s_waitcnt vmcnt(1)" ::: "memory"); }
        __builtin_amdgcn_s_barrier();
        __builtin_amdgcn_sched_barrier(0);
        if (s + 2 < 32)
            gl2lds16(e_src + (s + 2) * 32, lds_a + ((s + 2) % 3) * 2048 + tid * 8);
        const char* ab = lax + (s % 3) * 4096 + aoff0;
        bf16x8 af[4];
#pragma unroll
        for (int et = 0; et < 4; ++et) af[et] = *(const bf16x8*)(ab + et * 1024);
#pragma unroll
        for (int ntl = 0; ntl < 4; ++ntl) {
            bf16x8 bfrag = *(const bf16x8*)(lbx + boff0 + ntl * 2560 + 64 * s);
#pragma unroll
            for (int et = 0; et < 4; ++et)
                acc[et][ntl] = __builtin_amdgcn_mfma_f32_16x16x32_bf16(af[et], bfrag, acc[et][ntl], 0, 0, 0);
        }
    }
    __syncthreads();
    float (*red_s)[4] = (float(*)[4])smem;

    const int lseg  = l0 >> 8;
    const int lbase = l0 + wg * 4;
    float xv[4];
#pragma unroll
    for (int ntl = 0; ntl < 4; ++ntl) {
        int lr = lbase + ntl + 16 * c - 1;
        xv[ntl] = (lr >= 0 && lr < LL) ? X[b * LL + lr] : 0.f;
    }
#pragma unroll
    for (int et = 0; et < 4; ++et) {
#pragma unroll
        for (int r4 = 0; r4 < 4; ++r4) {
            float ssum = 0.f;
#pragma unroll
            for (int ntl = 0; ntl < 4; ++ntl) {
                int lr = lbase + ntl + 16 * c - 1;
                bool ok = (lr >= 0) && (lr < LL);
                float dd = ok ? (acc[et][ntl][r4] - xv[ntl]) : 0.f;
                ssum += dd * dd;
            }
            ssum += __shfl_xor(ssum, 1); ssum += __shfl_xor(ssum, 2);
            ssum += __shfl_xor(ssum, 4); ssum += __shfl_xor(ssum, 8);
            if (c == 0) red_s[et * 16 + g * 4 + r4][wg] = ssum;
        }
    }
    __syncthreads();
    if (tid < 64) {
        float tot = red_s[tid][0] + red_s[tid][1] + red_s[tid][2] + red_s[tid][3];
        recon_part[(b * 128 + row0 + tid) * 32 + lseg] = tot;
    }
}

// ---------------- kC: block0 = logits via w2cls; block1 = scalar losses --------
__global__ __launch_bounds__(256) void kC(const float* __restrict__ hbuf,
                                          const float* __restrict__ w2cls,
                                          const float* __restrict__ bias2,
                                          const float* __restrict__ recon_part,
                                          const float* __restrict__ vq_part,
                                          const int* __restrict__ hist,
                                          float* __restrict__ out) {
    const int tid = threadIdx.x;
    if (blockIdx.x == 0) {
        // logits[b,k] = (1/8 sum_t hbuf[b*8+t]) @ w2cls + bias2   (exact linearity)
        __shared__ float hsum[8][512];
        for (int idx = tid; idx < 4096; idx += 256) {
            const int b = idx >> 9, j = idx & 511;
            float s = 0.f;
#pragma unroll
            for (int t = 0; t < 8; ++t) s += hbuf[(b * 8 + t) * 512 + j];
            hsum[b][j] = s * 0.125f;
        }
        __syncthreads();
        if (tid < 80) {
            const int b = tid / 10, k = tid % 10;
            float a = bias2[k];
            for (int j = 0; j < 512; ++j) a = fmaf(hsum[b][j], w2cls[j * 10 + k], a);
            out[tid] = a;
        }
    } else {
        __shared__ float red[256];
        float s = 0.f;
        for (int i = tid; i < 32768; i += 256) s += recon_part[i];
        red[tid] = s;
        __syncthreads();
        for (int off = 128; off; off >>= 1) { if (tid < off) red[tid] += red[tid + off]; __syncthreads(); }
        if (tid == 0) out[81] = red[0] / 1047552.0f;
        __syncthreads();
        red[tid] = (tid < 128) ? vq_part[tid] : 0.f;
        __syncthreads();
        for (int off = 128; off; off >>= 1) { if (tid < off) red[tid] += red[tid + off]; __syncthreads(); }
        if (tid == 0) out[80] = 1.25f * red[0] / 130944.0f;
        __syncthreads();
        float avg = (float)hist[tid] * (1.0f / 128.0f);
        red[tid] = avg * logf(avg + EPSF);
        __syncthreads();
        for (int off = 128; off; off >>= 1) { if (tid < off) red[tid] += red[tid + off]; __syncthreads(); }
        if (tid == 0) out[82] = expf(-red[0]);
    }
}

extern "C" void kernel_launch(void* const* d_in, const int* in_sizes, int n_in,
                              void* d_out, int out_size, void* d_ws, size_t ws_size,
                              hipStream_t stream) {
    const float* X     = (const float*)d_in[0];
    const float* emb   = (const float*)d_in[1];
    const float* w1    = (const float*)d_in[2];
    const float* b1    = (const float*)d_in[3];
    const float* w2    = (const float*)d_in[4];
    const float* b2    = (const float*)d_in[5];
    const float* ln_g  = (const float*)d_in[6];
    const float* ln_b  = (const float*)d_in[7];
    const float* cls_w = (const float*)d_in[8];
    const float* cls_b = (const float*)d_in[9];
    float* out = (float*)d_out;

    float* Z            = (float*)d_ws;            // 130944
    float* vq_part      = Z + 130944;              // 128
    float* xnbuf        = vq_part + 128;           // 16384 (unused, layout keep)
    float* hdd          = xnbuf + 16384;           // 16384 (unused, layout keep)
    float* psum_part    = hdd + 16384;             // 65536  [lseg][b*256+e]
    float* recon_part   = psum_part + 65536;       // 32768
    int*   cmaxb        = (int*)(recon_part + 32768);  // 16384
    int*   codes        = cmaxb + 16384;           // 128
    int*   hist         = codes + 128;             // 256
    unsigned short* Xpad = (unsigned short*)(hist + 256);   // 8*10240 shorts
    unsigned short* Xodd = Xpad + 8 * XPS;                  // 8*10240 shorts
    unsigned short* Ebf  = Xodd + 8 * XPS;                  // 256*1024 shorts
    float* Etf           = (float*)(Ebf + 256 * 1024);      // 256*1024 floats
    float* enorm         = Etf + 256 * 1024;                // 256
    float* hbuf          = enorm + 256;                     // 64*512
    float* w2cls         = hbuf + 32768;                    // 512*10
    float* bias2         = w2cls + 5120;                    // 10

    k_pa<<<dim3(618), dim3(256), 0, stream>>>(X, emb, w2, b2, cls_w, cls_b,
                                              Xpad, Xodd, Ebf, Etf, enorm, hist, cmaxb, Z,
                                              w2cls, bias2);
    kA  <<<dim3(1024), dim3(256), 0, stream>>>(Z, (const float4*)Etf, enorm, emb, codes, hist,
                                               vq_part, Xpad, Xodd, Ebf, psum_part, cmaxb);
    kB  <<<dim3(576), dim3(256), 0, stream>>>(psum_part, cmaxb, ln_g, ln_b, w1, b1, hbuf,
                                              Xpad, Xodd, Ebf, codes, X, recon_part);
    kC  <<<dim3(2),   dim3(256), 0, stream>>>(hbuf, w2cls, bias2, recon_part, vq_part, hist, out);
}

// Round 19
// 119.688 us; speedup vs baseline: 1.0078x; 1.0078x over previous
//
#include <hip/hip_runtime.h>

#define KK 1023
#define LL 8184
#define LO 7162
#define XPS 10240
#define EPSF 1.1920928955078125e-07f
#define NEG_INF (-3.4028234663852886e+38f)

typedef short bf16x8 __attribute__((ext_vector_type(8)));
typedef float f32x4 __attribute__((ext_vector_type(4)));

__device__ __constant__ int c_pos[16] = {0,409,818,1227,1636,2045,2454,2863,
                                         3273,3682,4091,4500,4909,5318,5727,6137};

__device__ __forceinline__ unsigned short f2bf(float f) {
    unsigned u = __float_as_uint(f);
    unsigned r = (u + 0x7FFFu + ((u >> 16) & 1u)) >> 16;
    return (unsigned short)r;
}
__device__ __forceinline__ int fenc(float f) {
    int u = __float_as_int(f);
    return u >= 0 ? u : (~u) ^ 0x80000000;
}
__device__ __forceinline__ float fdec(int k) {
    int u = k >= 0 ? k : ~(k ^ 0x80000000);
    return __int_as_float(u);
}
__device__ __forceinline__ void gl2lds16(const void* g, void* l) {
    __builtin_amdgcn_global_load_lds(
        (const __attribute__((address_space(1))) void*)g,
        (__attribute__((address_space(3))) void*)l, 16, 0, 0);
}

// ---------------- K0: merged prep + autocov + init + w2cls precompute ----------
__global__ __launch_bounds__(256) void k_pa(const float* __restrict__ X,
                                            const float* __restrict__ emb,
                                            const float* __restrict__ w2,
                                            const float* __restrict__ b2,
                                            const float* __restrict__ cls_w,
                                            const float* __restrict__ cls_b,
                                            unsigned short* __restrict__ Xpad,
                                            unsigned short* __restrict__ Xodd,
                                            unsigned short* __restrict__ Ebf,
                                            float* __restrict__ Etf,
                                            float* __restrict__ enorm,
                                            int* __restrict__ hist,
                                            int* __restrict__ cmax,
                                            float* __restrict__ Z,
                                            float* __restrict__ w2cls,
                                            float* __restrict__ bias2) {
    __shared__ __align__(16) float xw[2048];
    __shared__ float red[256];
    const int q = blockIdx.x;
    const int tid = threadIdx.x;
    if (q < 256) {
        const int fi = q >> 1, half = q & 1;
        const int b = fi >> 4, h = fi & 15;
        const float* xp = X + b * LL + c_pos[h];
        float lmax = 0.f;
        for (int j = tid; j < KK; j += 256) {
            float v = xp[j];
            xw[j] = v;
            lmax = fmaxf(lmax, fabsf(v));
        }
        red[tid] = lmax;
        __syncthreads();
        for (int off = 128; off; off >>= 1) {
            if (tid < off) red[tid] = fmaxf(red[tid], red[tid + off]);
            __syncthreads();
        }
        float fmx = red[0];
        if (fmx == 0.f) fmx = EPSF;
        __syncthreads();
        for (int j = tid; j < KK; j += 256) {
            float v = xw[j];
            float win = 0.5f * (1.0f - cosf(6.28318530717958647692f * (float)j / 1023.0f));
            float w = v * win / fmx;
            xw[j] = w;
            xw[j + KK] = w;   // duplicate: c[m] = sum_j xw[j]*xw[j+m]
        }
        __syncthreads();

        const int m2 = half * 512 + 2 * tid;
        const int mh = m2 >> 1;
        const float2* X2 = (const float2*)xw;
        float a0 = 0.f, a1 = 0.f;
        float2 F = X2[mh];
#pragma unroll 2
        for (int jh = 0; jh < 510; jh += 2) {
            float2 xj0 = X2[jh];
            float2 xj1 = X2[jh + 1];
            float2 G0 = X2[mh + jh + 1];
            float2 G1 = X2[mh + jh + 2];
            a0 = fmaf(xj0.x, F.x, a0);
            a0 = fmaf(xj0.y, F.y, a0);
            a1 = fmaf(xj0.x, F.y, a1);
            a1 = fmaf(xj0.y, G0.x, a1);
            a0 = fmaf(xj1.x, G0.x, a0);
            a0 = fmaf(xj1.y, G0.y, a0);
            a1 = fmaf(xj1.x, G0.y, a1);
            a1 = fmaf(xj1.y, G1.x, a1);
            F = G1;
        }
        {   // jh = 510 single step
            float2 xj = X2[510];
            float2 G = X2[mh + 511];
            a0 = fmaf(xj.x, F.x, a0);
            a0 = fmaf(xj.y, F.y, a0);
            a1 = fmaf(xj.x, F.y, a1);
            a1 = fmaf(xj.y, G.x, a1);
            F = G;
        }
        float xt = xw[1022];
        a0 = fmaf(xt, F.x, a0);
        a1 = fmaf(xt, F.y, a1);
        float* zrow = Z + fi * KK;
        int i0 = m2 + 512; if (i0 >= KK) i0 -= KK;   // Z[i] = c[(i+511)%1023]
        zrow[i0] = a0;
        if (m2 + 1 < KK) {
            int i1 = m2 + 513; if (i1 >= KK) i1 -= KK;
            zrow[i1] = a1;
        }
    } else if (q < 288) {
        const int qq = q - 256;
        const int b = qq >> 2, seg = qq & 3;
        for (int i = seg * 2560 + tid; i < (seg + 1) * 2560; i += 256) {
            unsigned short v = 0, vo = 0;
            if (i >= 512 && i < 512 + LL) v = f2bf(X[b * LL + (i - 512)]);
            const int i1 = i + 1;
            if (i1 >= 512 && i1 < 512 + LL) vo = f2bf(X[b * LL + (i1 - 512)]);
            Xpad[b * XPS + i] = v;
            Xodd[b * XPS + i] = vo;        // Xodd[i] = Xpad[i+1]
        }
    } else if (q < 544) {
        const int e = q - 288;
        const float* er = emb + e * KK;
        float nrm = 0.f;
        for (int k = tid; k < 1024; k += 256) {
            float v = (k < KK) ? er[k] : 0.f;
            Ebf[e * 1024 + k] = (k < KK) ? f2bf(v) : (unsigned short)0;
            Etf[(k >> 2) * 1024 + e * 4 + (k & 3)] = v;   // float4 [t4][e]
            nrm = fmaf(v, v, nrm);
        }
        red[tid] = nrm;
        __syncthreads();
        for (int off = 128; off; off >>= 1) {
            if (tid < off) red[tid] += red[tid + off];
            __syncthreads();
        }
        if (tid == 0) enorm[e] = red[0];
    } else if (q < 608) {
        const int i = (q - 544) * 256 + tid;
        cmax[i] = INT_MIN;
        if (q == 544) hist[tid] = 0;
    } else {
        const int k = q - 608;
#pragma unroll
        for (int jj = 0; jj < 2; ++jj) {
            const int j = tid + jj * 256;
            const float* wr = w2 + j * 256;
            float a = 0.f;
            for (int e = 0; e < 256; ++e) a = fmaf(wr[e], cls_w[e * 10 + k], a);
            w2cls[j * 10 + k] = a;
        }
        if (tid == 0) {
            float a = cls_b[k];
            for (int e = 0; e < 256; ++e) a = fmaf(b2[e], cls_w[e * 10 + k], a);
            bias2[k] = a;
        }
    }
}

// ---------------- kA: fused VQ (blocks 0-127) + proj-GEMM (blocks 128-1023) ----
// Proj block decode is XCD-swizzled (bijective: 896 = 8 XCDs x 112): blocks
// with u&7 == xcd share row0 (64 Ebf rows) + a 4-b Xpad slice -> per-XCD L2
// working set ~300KB instead of the full ~2.7MB.
__global__ __launch_bounds__(256, 4) void kA(const float* __restrict__ Z,
                                             const float4* __restrict__ Et4,
                                             const float* __restrict__ enorm,
                                             const float* __restrict__ emb,
                                             int* __restrict__ codes,
                                             int* __restrict__ hist,
                                             float* __restrict__ vq_part,
                                             const unsigned short* __restrict__ Xpad,
                                             const unsigned short* __restrict__ Xodd,
                                             const unsigned short* __restrict__ Ebf,
                                             float* __restrict__ psum_part,
                                             int* __restrict__ cmax) {
    __shared__ __align__(16) char smem[32768];   // 20480 B (lds_b / red_s) + 12288 B (A x3)
    const int tid = threadIdx.x;
    const int bi = blockIdx.x;
    if (bi < 128) {
        // ================= VQ branch =================
        float* zl  = (float*)smem;
        float* zm2 = (float*)(smem + 4096);
        float* rv  = (float*)(smem + 8192);
        int*   ri  = (int*)(smem + 9216);
        const int fi = bi;
        const float* zrow = Z + fi * KK;
        for (int t = tid; t < 1024; t += 256) {
            float z = (t < KK) ? zrow[t] : 0.f;
            if (t < KK) zl[t] = z;
            zm2[t] = -2.f * z;
        }
        __syncthreads();

        float d = enorm[tid];
        const float4* zp = (const float4*)zm2;
        const float4* ep = Et4 + tid;
#pragma unroll 8
        for (int t4 = 0; t4 < 256; ++t4) {
            float4 ev = ep[t4 * 256];
            float4 zv = zp[t4];
            d = fmaf(zv.x, ev.x, d);
            d = fmaf(zv.y, ev.y, d);
            d = fmaf(zv.z, ev.z, d);
            d = fmaf(zv.w, ev.w, d);
        }
        rv[tid] = d; ri[tid] = tid;
        __syncthreads();
        for (int off = 128; off; off >>= 1) {
            if (tid < off) {
                float v2 = rv[tid + off]; int i2 = ri[tid + off];
                if (v2 < rv[tid] || (v2 == rv[tid] && i2 < ri[tid])) { rv[tid] = v2; ri[tid] = i2; }
            }
            __syncthreads();
        }
        const int code = ri[0];
        if (tid == 0) { codes[fi] = code; atomicAdd(&hist[code], 1); }

        const float* qr = emb + code * KK;
        float s = 0.f;
        for (int t = tid; t < KK; t += 256) { float dd = qr[t] - zl[t]; s += dd * dd; }
        __syncthreads();
        rv[tid] = s;
        __syncthreads();
        for (int off = 128; off; off >>= 1) {
            if (tid < off) rv[tid] += rv[tid + off];
            __syncthreads();
        }
        if (tid == 0) vq_part[fi] = rv[0];
        return;
    }
    // ================= proj-GEMM branch (counted-vmcnt pipeline) =================
    unsigned short* lds_b = (unsigned short*)smem;                 // 20480 B
    unsigned short* lds_a = (unsigned short*)(smem + 20480);       // 3 x 4096 B
    const int lane = tid & 63;
    const int c = lane & 15, g = lane >> 4;
    const int wg = tid >> 6;

    // XCD swizzle: u&7 = xcd; row0 from xcd>>1; (b,lseg) from idx + (xcd&1)*112
    const int u = bi - 128;
    const int xcd = u & 7;
    const int idx = u >> 3;                     // 0..111
    const int row0 = (xcd >> 1) * 64;
    const int j = idx + (xcd & 1) * 112;        // 0..223
    const int b = j / 28;
    const int l0 = (j % 28) * 256;
    const int xw0 = 512 + l0;

    {
        const unsigned short* base_e = Xpad + b * XPS + xw0;
        const unsigned short* base_o = Xodd + b * XPS + xw0;
        for (int k = tid; k < 1280; k += 256) {
            const int wdw = k / 160;
            const int p = k - wdw * 160;
            const unsigned short* src = (wdw & 1) ? (base_o + wdw - 1 + p * 8)
                                                  : (base_e + wdw + p * 8);
            gl2lds16(src, lds_b + k * 8);
        }
    }
    const int r_lds = tid >> 2, q4 = tid & 3;
    const unsigned short* e_src = Ebf + (row0 + r_lds) * 1024 + q4 * 8;
    gl2lds16(e_src,      lds_a + tid * 8);            // A(0) -> buf0
    gl2lds16(e_src + 32, lds_a + 2048 + tid * 8);     // A(1) -> buf1
    __syncthreads();

    f32x4 acc[4][4];
#pragma unroll
    for (int i = 0; i < 4; ++i)
#pragma unroll
        for (int jq = 0; jq < 4; ++jq) acc[i][jq] = (f32x4){0.f, 0.f, 0.f, 0.f};

    const char* lax = (const char*)lds_a;
    const char* lbx = (const char*)lds_b;
    const int boff0 = (wg & 1) * 10240 + ((wg >> 1) << 4) + 32 * c + 16 * g;
    const int aoff0 = c * 64 + g * 16;

#pragma unroll 1
    for (int s = 0; s < 32; ++s) {
        if (s == 31) { asm volatile("s_waitcnt vmcnt(0)" ::: "memory"); }
        else         { asm volatile("s_waitcnt vmcnt(1)" ::: "memory"); }
        __builtin_amdgcn_s_barrier();
        __builtin_amdgcn_sched_barrier(0);
        if (s + 2 < 32)
            gl2lds16(e_src + (s + 2) * 32, lds_a + ((s + 2) % 3) * 2048 + tid * 8);
        const char* ab = lax + (s % 3) * 4096 + aoff0;
        bf16x8 af[4];
#pragma unroll
        for (int et = 0; et < 4; ++et) af[et] = *(const bf16x8*)(ab + et * 1024);
#pragma unroll
        for (int ntl = 0; ntl < 4; ++ntl) {
            bf16x8 bfrag = *(const bf16x8*)(lbx + boff0 + ntl * 2560 + 64 * s);
#pragma unroll
            for (int et = 0; et < 4; ++et)
                acc[et][ntl] = __builtin_amdgcn_mfma_f32_16x16x32_bf16(af[et], bfrag, acc[et][ntl], 0, 0, 0);
        }
    }
    __syncthreads();
    float (*red_s)[4] = (float(*)[4])smem;

    const int lseg  = l0 >> 8;
    const int lbase = l0 + wg * 4;
    const int ch0 = lbase / 896;
#pragma unroll
    for (int et = 0; et < 4; ++et) {
#pragma unroll
        for (int r4 = 0; r4 < 4; ++r4) {
            float ssum = 0.f, m0 = NEG_INF, m1 = NEG_INF;
#pragma unroll
            for (int ntl = 0; ntl < 4; ++ntl) {
                float v = acc[et][ntl][r4];
                int l = lbase + ntl + 16 * c;
                bool ok = l < LO;
                ssum += ok ? v : 0.f;
                int ch = l / 896;
                if (ok && ch == ch0) m0 = fmaxf(m0, v);
                if (ok && ch != ch0) m1 = fmaxf(m1, v);
            }
            ssum += __shfl_xor(ssum, 1); ssum += __shfl_xor(ssum, 2);
            ssum += __shfl_xor(ssum, 4); ssum += __shfl_xor(ssum, 8);
            m0 = fmaxf(m0, __shfl_xor(m0, 1)); m0 = fmaxf(m0, __shfl_xor(m0, 2));
            m0 = fmaxf(m0, __shfl_xor(m0, 4)); m0 = fmaxf(m0, __shfl_xor(m0, 8));
            m1 = fmaxf(m1, __shfl_xor(m1, 1)); m1 = fmaxf(m1, __shfl_xor(m1, 2));
            m1 = fmaxf(m1, __shfl_xor(m1, 4)); m1 = fmaxf(m1, __shfl_xor(m1, 8));
            if (c == 0) {
                int eidx = et * 16 + g * 4 + r4;
                red_s[eidx][wg] = ssum;
                int e = row0 + eidx;
                int cb = (b * 256 + e) * 8;
                if (m0 > NEG_INF && ch0 < 8)     atomicMax(&cmax[cb + ch0], fenc(m0));
                if (m1 > NEG_INF && ch0 + 1 < 8) atomicMax(&cmax[cb + ch0 + 1], fenc(m1));
            }
        }
    }
    __syncthreads();
    if (tid < 64) {
        float tot = red_s[tid][0] + red_s[tid][1] + red_s[tid][2] + red_s[tid][3];
        psum_part[lseg * 2048 + b * 256 + row0 + tid] = tot;   // [lseg][b*256+e]
    }
}

// ---------------- kB: fused LN+FFN1 (blocks 0-63) + recon-GEMM (blocks 64-575) --
__global__ __launch_bounds__(256, 4) void kB(const float* __restrict__ psum_part,
                                             const int* __restrict__ cmax,
                                             const float* __restrict__ ln_g,
                                             const float* __restrict__ ln_b,
                                             const float* __restrict__ w1,
                                             const float* __restrict__ b1,
                                             float* __restrict__ hbuf,
                                             const unsigned short* __restrict__ Xpad,
                                             const unsigned short* __restrict__ Xodd,
                                             const unsigned short* __restrict__ Ebf,
                                             const int* __restrict__ codes,
                                             const float* __restrict__ X,
                                             float* __restrict__ recon_part) {
    __shared__ __align__(16) char smem[32768];
    const int tid = threadIdx.x;
    const int bi = blockIdx.x;
    if (bi < 64) {
        // ================= LN + FFN1 branch =================
        float* red  = (float*)smem;
        float* red2 = (float*)(smem + 1024);
        float* xr   = (float*)(smem + 2048);
        const int bt = bi;
        const int t = bt & 7;
        const int b = bt >> 3;
        const int e = tid;
        const float* ps = psum_part + b * 256 + e;
        float sm = 0.f;
#pragma unroll
        for (int s = 0; s < 28; ++s) sm += ps[s * 2048];
        float m = sm * (1.0f / 7162.0f);
        const int cb = (b * 256 + e) << 3;
        float v = (t < 7) ? fdec(cmax[cb + t]) : fmaxf(fdec(cmax[cb + 7]), m);
        red[e] = v; red2[e] = v * v;
        __syncthreads();
        for (int off = 128; off; off >>= 1) {
            if (e < off) { red[e] += red[e + off]; red2[e] += red2[e + off]; }
            __syncthreads();
        }
        float mu  = red[0] * (1.0f / 256.0f);
        float var = red2[0] * (1.0f / 256.0f) - mu * mu;
        float rr = 1.0f / sqrtf(var + 1e-5f);
        xr[e] = (v - mu) * rr * ln_g[e] + ln_b[e];
        __syncthreads();

        float a0 = 0.f, a1 = 0.f;
#pragma unroll 4
        for (int ee = 0; ee < 256; ++ee) {
            float xv = xr[ee];
            a0 = fmaf(xv, w1[ee * 512 + e], a0);
            a1 = fmaf(xv, w1[ee * 512 + 256 + e], a1);
        }
        hbuf[bt * 512 + e]       = fmaxf(a0 + b1[e], 0.f);
        hbuf[bt * 512 + 256 + e] = fmaxf(a1 + b1[256 + e], 0.f);
        return;
    }
    // ================= recon-GEMM branch (counted-vmcnt pipeline) ==============
    unsigned short* lds_b = (unsigned short*)smem;
    unsigned short* lds_a = (unsigned short*)(smem + 20480);
    const int lane = tid & 63;
    const int c = lane & 15, g = lane >> 4;
    const int wg = tid >> 6;

    // XCD swizzle (bijective: 512 = 8 x 64): b = rb&7 -> each XCD one b's Xpad
    const int rb = bi - 64;
    const int b = rb & 7;
    const int r = rb >> 3;                 // 0..63
    const int row0 = (r >> 5) * 64;
    const int l0 = (r & 31) * 256;
    const int xw0 = l0;

    {
        const unsigned short* base_e = Xpad + b * XPS + xw0;
        const unsigned short* base_o = Xodd + b * XPS + xw0;
        for (int k = tid; k < 1280; k += 256) {
            const int wdw = k / 160;
            const int p = k - wdw * 160;
            const unsigned short* src = (wdw & 1) ? (base_o + wdw - 1 + p * 8)
                                                  : (base_e + wdw + p * 8);
            gl2lds16(src, lds_b + k * 8);
        }
    }
    const int r_lds = tid >> 2, q4 = tid & 3;
    const unsigned short* e_src = Ebf + codes[row0 + r_lds] * 1024 + q4 * 8;
    gl2lds16(e_src,      lds_a + tid * 8);
    gl2lds16(e_src + 32, lds_a + 2048 + tid * 8);
    __syncthreads();

    f32x4 acc[4][4];
#pragma unroll
    for (int i = 0; i < 4; ++i)
#pragma unroll
        for (int jq = 0; jq < 4; ++jq) acc[i][jq] = (f32x4){0.f, 0.f, 0.f, 0.f};

    const char* lax = (const char*)lds_a;
    const char* lbx = (const char*)lds_b;
    const int boff0 = (wg & 1) * 10240 + ((wg >> 1) << 4) + 32 * c + 16 * g;
    const int aoff0 = c * 64 + g * 16;

#pragma unroll 1
    for (int s = 0; s < 32; ++s) {
        if (s == 31) { asm volatile("s_waitcnt vmcnt(0)" ::: "memory"); }
        else         { asm volatile("s_waitcnt vmcnt(1)" ::: "memory"); }
        __builtin_amdgcn_s_barrier();
        __builtin_amdgcn_sched_barrier(0);
        if (s + 2 < 32)
            gl2lds16(e_src + (s + 2) * 32, lds_a + ((s + 2) % 3) * 2048 + tid * 8);
        const char* ab = lax + (s % 3) * 4096 + aoff0;
        bf16x8 af[4];
#pragma unroll
        for (int et = 0; et < 4; ++et) af[et] = *(const bf16x8*)(ab + et * 1024);
#pragma unroll
        for (int ntl = 0; ntl < 4; ++ntl) {
            bf16x8 bfrag = *(const bf16x8*)(lbx + boff0 + ntl * 2560 + 64 * s);
#pragma unroll
            for (int et = 0; et < 4; ++et)
                acc[et][ntl] = __builtin_amdgcn_mfma_f32_16x16x32_bf16(af[et], bfrag, acc[et][ntl], 0, 0, 0);
        }
    }
    __syncthreads();
    float (*red_s)[4] = (float(*)[4])smem;

    const int lseg  = l0 >> 8;
    const int lbase = l0 + wg * 4;
    float xv[4];
#pragma unroll
    for (int ntl = 0; ntl < 4; ++ntl) {
        int lr = lbase + ntl + 16 * c - 1;
        xv[ntl] = (lr >= 0 && lr < LL) ? X[b * LL + lr] : 0.f;
    }
#pragma unroll
    for (int et = 0; et < 4; ++et) {
#pragma unroll
        for (int r4 = 0; r4 < 4; ++r4) {
            float ssum = 0.f;
#pragma unroll
            for (int ntl = 0; ntl < 4; ++ntl) {
                int lr = lbase + ntl + 16 * c - 1;
                bool ok = (lr >= 0) && (lr < LL);
                float dd = ok ? (acc[et][ntl][r4] - xv[ntl]) : 0.f;
                ssum += dd * dd;
            }
            ssum += __shfl_xor(ssum, 1); ssum += __shfl_xor(ssum, 2);
            ssum += __shfl_xor(ssum, 4); ssum += __shfl_xor(ssum, 8);
            if (c == 0) red_s[et * 16 + g * 4 + r4][wg] = ssum;
        }
    }
    __syncthreads();
    if (tid < 64) {
        float tot = red_s[tid][0] + red_s[tid][1] + red_s[tid][2] + red_s[tid][3];
        recon_part[(b * 128 + row0 + tid) * 32 + lseg] = tot;
    }
}

// ---------------- kC: block0 = logits via w2cls; block1 = scalar losses --------
__global__ __launch_bounds__(256) void kC(const float* __restrict__ hbuf,
                                          const float* __restrict__ w2cls,
                                          const float* __restrict__ bias2,
                                          const float* __restrict__ recon_part,
                                          const float* __restrict__ vq_part,
                                          const int* __restrict__ hist,
                                          float* __restrict__ out) {
    const int tid = threadIdx.x;
    if (blockIdx.x == 0) {
        __shared__ float hsum[8][512];
        for (int idx = tid; idx < 4096; idx += 256) {
            const int b = idx >> 9, j = idx & 511;
            float s = 0.f;
#pragma unroll
            for (int t = 0; t < 8; ++t) s += hbuf[(b * 8 + t) * 512 + j];
            hsum[b][j] = s * 0.125f;
        }
        __syncthreads();
        if (tid < 80) {
            const int b = tid / 10, k = tid % 10;
            float a = bias2[k];
            for (int j = 0; j < 512; ++j) a = fmaf(hsum[b][j], w2cls[j * 10 + k], a);
            out[tid] = a;
        }
    } else {
        __shared__ float red[256];
        float s = 0.f;
        for (int i = tid; i < 32768; i += 256) s += recon_part[i];
        red[tid] = s;
        __syncthreads();
        for (int off = 128; off; off >>= 1) { if (tid < off) red[tid] += red[tid + off]; __syncthreads(); }
        if (tid == 0) out[81] = red[0] / 1047552.0f;
        __syncthreads();
        red[tid] = (tid < 128) ? vq_part[tid] : 0.f;
        __syncthreads();
        for (int off = 128; off; off >>= 1) { if (tid < off) red[tid] += red[tid + off]; __syncthreads(); }
        if (tid == 0) out[80] = 1.25f * red[0] / 130944.0f;
        __syncthreads();
        float avg = (float)hist[tid] * (1.0f / 128.0f);
        red[tid] = avg * logf(avg + EPSF);
        __syncthreads();
        for (int off = 128; off; off >>= 1) { if (tid < off) red[tid] += red[tid + off]; __syncthreads(); }
        if (tid == 0) out[82] = expf(-red[0]);
    }
}

extern "C" void kernel_launch(void* const* d_in, const int* in_sizes, int n_in,
                              void* d_out, int out_size, void* d_ws, size_t ws_size,
                              hipStream_t stream) {
    const float* X     = (const float*)d_in[0];
    const float* emb   = (const float*)d_in[1];
    const float* w1    = (const float*)d_in[2];
    const float* b1    = (const float*)d_in[3];
    const float* w2    = (const float*)d_in[4];
    const float* b2    = (const float*)d_in[5];
    const float* ln_g  = (const float*)d_in[6];
    const float* ln_b  = (const float*)d_in[7];
    const float* cls_w = (const float*)d_in[8];
    const float* cls_b = (const float*)d_in[9];
    float* out = (float*)d_out;

    float* Z            = (float*)d_ws;            // 130944
    float* vq_part      = Z + 130944;              // 128
    float* xnbuf        = vq_part + 128;           // 16384 (unused, layout keep)
    float* hdd          = xnbuf + 16384;           // 16384 (unused, layout keep)
    float* psum_part    = hdd + 16384;             // 65536  [lseg][b*256+e]
    float* recon_part   = psum_part + 65536;       // 32768
    int*   cmaxb        = (int*)(recon_part + 32768);  // 16384
    int*   codes        = cmaxb + 16384;           // 128
    int*   hist         = codes + 128;             // 256
    unsigned short* Xpad = (unsigned short*)(hist + 256);   // 8*10240 shorts
    unsigned short* Xodd = Xpad + 8 * XPS;                  // 8*10240 shorts
    unsigned short* Ebf  = Xodd + 8 * XPS;                  // 256*1024 shorts
    float* Etf           = (float*)(Ebf + 256 * 1024);      // 256*1024 floats
    float* enorm         = Etf + 256 * 1024;                // 256
    float* hbuf          = enorm + 256;                     // 64*512
    float* w2cls         = hbuf + 32768;                    // 512*10
    float* bias2         = w2cls + 5120;                    // 10

    k_pa<<<dim3(618), dim3(256), 0, stream>>>(X, emb, w2, b2, cls_w, cls_b,
                                              Xpad, Xodd, Ebf, Etf, enorm, hist, cmaxb, Z,
                                              w2cls, bias2);
    kA  <<<dim3(1024), dim3(256), 0, stream>>>(Z, (const float4*)Etf, enorm, emb, codes, hist,
                                               vq_part, Xpad, Xodd, Ebf, psum_part, cmaxb);
    kB  <<<dim3(576), dim3(256), 0, stream>>>(psum_part, cmaxb, ln_g, ln_b, w1, b1, hbuf,
                                              Xpad, Xodd, Ebf, codes, X, recon_part);
    kC  <<<dim3(2),   dim3(256), 0, stream>>>(hbuf, w2cls, bias2, recon_part, vq_part, hist, out);
}